// Round 6
// baseline (307.990 us; speedup 1.0000x reference)
//
#include <hip/hip_runtime.h>

// FeatureAttentionLayer: B=64, NF=256, W=128, E=128, K=32 — ALL FP32.
#define NFEAT 256
#define TK    32
#define WIN   128
#define EMB   128
#define NBATCH 64
#define ALPHA 0.2f
#define MROWS (NBATCH * NFEAT)   // 16384 rows of Wx

__device__ __forceinline__ float lrelu(float x) { return x > 0.f ? x : ALPHA * x; }

// ---------------------------------------------------------------------------
// Kernel 1: Wx = x @ W + b  (M=16384, K=128, N=128), fp32 VALU.
// (unchanged: twice-validated R0 32-row version)
// ---------------------------------------------------------------------------
__global__ __launch_bounds__(256) void gemm_wx(
    const float* __restrict__ x,      // 16384 x 128
    const float* __restrict__ W,      // 128 x 128 (row-major [k][n])
    const float* __restrict__ bn,     // 128
    const float* __restrict__ avec,   // 256
    float* __restrict__ wx,           // out: 16384 x 128
    float* __restrict__ s1, float* __restrict__ s2) {
  __shared__ float xT[WIN][36];      // [k][r], padded
  int t = threadIdx.x;
  int rows0 = blockIdx.x * 32;

  {
    int r = t >> 3, jc = t & 7;
    const float4* src = (const float4*)(x + (long)(rows0 + r) * WIN + jc * 16);
#pragma unroll
    for (int u = 0; u < 4; ++u) {
      float4 v = src[u];
      int c = jc * 16 + u * 4;
      xT[c + 0][r] = v.x; xT[c + 1][r] = v.y; xT[c + 2][r] = v.z; xT[c + 3][r] = v.w;
    }
  }
  __syncthreads();

  int g = t >> 5, ct = t & 31;
  int r0 = g * 4;
  int c0 = ct * 4;

  float acc[4][4];
#pragma unroll
  for (int i = 0; i < 4; ++i)
#pragma unroll
    for (int j = 0; j < 4; ++j) acc[i][j] = 0.f;

#pragma unroll 4
  for (int k = 0; k < WIN; ++k) {
    float4 xv = *(const float4*)&xT[k][r0];
    float4 wv = *(const float4*)(W + k * EMB + c0);
    acc[0][0] += xv.x * wv.x; acc[0][1] += xv.x * wv.y; acc[0][2] += xv.x * wv.z; acc[0][3] += xv.x * wv.w;
    acc[1][0] += xv.y * wv.x; acc[1][1] += xv.y * wv.y; acc[1][2] += xv.y * wv.z; acc[1][3] += xv.y * wv.w;
    acc[2][0] += xv.z * wv.x; acc[2][1] += xv.z * wv.y; acc[2][2] += xv.z * wv.z; acc[2][3] += xv.z * wv.w;
    acc[3][0] += xv.w * wv.x; acc[3][1] += xv.w * wv.y; acc[3][2] += xv.w * wv.z; acc[3][3] += xv.w * wv.w;
  }

  float4 bv = *(const float4*)(bn + c0);
#pragma unroll
  for (int i = 0; i < 4; ++i) {
    acc[i][0] += bv.x; acc[i][1] += bv.y; acc[i][2] += bv.z; acc[i][3] += bv.w;
  }

#pragma unroll
  for (int i = 0; i < 4; ++i) {
    float4 o = make_float4(acc[i][0], acc[i][1], acc[i][2], acc[i][3]);
    *(float4*)(wx + (long)(rows0 + r0 + i) * EMB + c0) = o;
  }

  float4 a1 = *(const float4*)(avec + c0);
  float4 a2 = *(const float4*)(avec + EMB + c0);
  float p1[4], p2[4];
#pragma unroll
  for (int i = 0; i < 4; ++i) {
    p1[i] = acc[i][0] * a1.x + acc[i][1] * a1.y + acc[i][2] * a1.z + acc[i][3] * a1.w;
    p2[i] = acc[i][0] * a2.x + acc[i][1] * a2.y + acc[i][2] * a2.z + acc[i][3] * a2.w;
  }
#pragma unroll
  for (int i = 0; i < 4; ++i) {
#pragma unroll
    for (int m = 1; m < 32; m <<= 1) {
      p1[i] += __shfl_xor(p1[i], m, 64);
      p2[i] += __shfl_xor(p2[i], m, 64);
    }
  }
  if (ct == 0) {
#pragma unroll
    for (int i = 0; i < 4; ++i) {
      s1[rows0 + r0 + i] = p1[i];
      s2[rows0 + r0 + i] = p2[i];
    }
  }
}

// ---------------------------------------------------------------------------
// Kernel A: softmax coefficients for ALL (b,n,k), full-thread utilization,
// no streaming work behind a barrier.
// Block: 256 thr = 8 (b,n) groups x 32 k. 2048 blocks.
// Emits pk[bidx*32+k] = { att (bits), wx_row } — one 8-B record per (bidx,k),
// so the streamer needs a single broadcast load per output row.
// Phase-1 math identical to the thrice-verified attn_out phase 1.
// ---------------------------------------------------------------------------
__global__ __launch_bounds__(256) void attn_coef(
    const int* __restrict__ edge,      // 256*32 ints (row 0 of edge_indices)
    const float* __restrict__ biasn,   // 256*32
    const float* __restrict__ s1, const float* __restrict__ s2,
    int2* __restrict__ pk) {           // out: 16384*32 {att,row}
  int tid = threadIdx.x;
  int k  = tid & 31;
  int nl = tid >> 5;                   // 0..7
  int bidx = blockIdx.x * 8 + nl;
  int b = bidx >> 8, n = bidx & 255;

  int nbr = edge[n * TK + k];
  float v;
  if (k < 16) {
    v = s1[b * NFEAT + n] + s2[b * NFEAT + n];
  } else {
    int j0 = 2 * k - 32;
    int r0 = edge[n * TK + j0];
    int r1 = edge[n * TK + j0 + 1];
    v = s1[b * NFEAT + r0] + s2[b * NFEAT + r1];
  }
  v = lrelu(v);
  float bb = biasn[n * TK + k];
  if (bb != bb) bb = 0.f;              // nan_to_num
  v += bb;
  // 32-wide reduce: masks 1..16 with width 64 stay inside each 32-lane half,
  // which is exactly one (b,n) group.
  float mx = v;
#pragma unroll
  for (int m = 1; m < 32; m <<= 1) mx = fmaxf(mx, __shfl_xor(mx, m, 64));
  float ex = __expf(v - mx);
  float sum = ex;
#pragma unroll
  for (int m = 1; m < 32; m <<= 1) sum += __shfl_xor(sum, m, 64);
  float att = ex / sum;

  int2 rec;
  rec.x = __float_as_int(att);
  rec.y = b * NFEAT + nbr;             // absolute wx row
  pk[bidx * TK + k] = rec;             // coalesced 8 B/lane
}

// ---------------------------------------------------------------------------
// Kernel B: pure grid-stride streamer. No LDS, no barrier, no serial
// section. i indexes output float4s (16,777,216 total).
//   pk[i>>5] is uniform across each 32-lane half -> one broadcast load.
//   wx gather is L2-resident (8 MiB); store is per-wave 1 KiB contiguous.
// Conventional bounded grid-stride loop (R5: de-risked form, semantics
// identical to R4's fixed-count version).
// ---------------------------------------------------------------------------
__global__ __launch_bounds__(256) void stream_out(
    const int2* __restrict__ pk,       // 16384*32 {att,row}
    const float* __restrict__ wx,      // 16384 x 128
    float4* __restrict__ out) {        // 16,777,216 float4
  const unsigned total = (unsigned)MROWS * TK * (EMB / 4);  // 16,777,216
  unsigned gsz = gridDim.x * blockDim.x;
  for (unsigned i = blockIdx.x * blockDim.x + threadIdx.x; i < total; i += gsz) {
    int2 p = pk[i >> 5];
    float ak = __int_as_float(p.x);
    float4 v = *(const float4*)(wx + (long)p.y * EMB + (i & 31) * 4);
    float4 o = make_float4(lrelu(ak * v.x), lrelu(ak * v.y),
                           lrelu(ak * v.z), lrelu(ak * v.w));
    out[i] = o;
  }
}

extern "C" void kernel_launch(void* const* d_in, const int* in_sizes, int n_in,
                              void* d_out, int out_size, void* d_ws, size_t ws_size,
                              hipStream_t stream) {
  const float* x_n    = (const float*)d_in[0];
  // d_in[1] x_e: unused by reference
  const int*   edge   = (const int*)d_in[2];
  // d_in[3] all_embeddings: unused by reference
  const float* W_n    = (const float*)d_in[4];
  const float* b_n    = (const float*)d_in[5];
  const float* a_v    = (const float*)d_in[6];
  const float* bias_n = (const float*)d_in[7];
  float* out = (float*)d_out;

  char* ws = (char*)d_ws;
  float* wx = (float*)ws;                                   // 8 MB
  float* s1 = (float*)(ws + (8 << 20));                     // 64 KB
  float* s2 = (float*)(ws + (8 << 20) + (64 << 10));        // 64 KB
  int2*  pk = (int2*)(ws + (8 << 20) + (128 << 10));        // 4 MB

  gemm_wx<<<MROWS / 32, 256, 0, stream>>>(x_n, W_n, b_n, a_v, wx, s1, s2);
  attn_coef<<<MROWS / 8, 256, 0, stream>>>(edge, bias_n, s1, s2, pk);
  stream_out<<<2048, 256, 0, stream>>>(pk, wx, (float4*)out);
}